// Round 1
// baseline (86463.940 us; speedup 1.0000x reference)
//
#include <hip/hip_runtime.h>
#include <cstddef>
#include <cstdint>

#define NODE 207
#define HID 16
#define BATCH 64
#define TSTEPS 12
#define HIDDEN 6624            // NODE*HID*2
#define K_IH 16560             // NODE*HID*5
#define K_IH4 4140             // K_IH/4
#define H4 1656                // HIDDEN/4

// ---------------------------------------------------------------------------
// Kernel A: build transposed input inpT (K_IH, 64) for outer step t.
//   inp[b, i*207+n]              = conv_w[i] * spline[t,b,n,1]        (k < 3312)
//   inp[b, 3312 + n*64+i*4+kk*2+0] = f[b,n,i,kk] = tanh(h@Wf+bf)
//   inp[b, 3312 + n*64+i*4+kk*2+1] = fg[b,n,i,kk] = sum_j g[i,j]*f[j,kk]
// One block per (b, n). inpT[k*64 + b].
// ---------------------------------------------------------------------------
__global__ __launch_bounds__(256) void build_inp_kernel(
    const float* __restrict__ spline,   // (12,64,207,2)
    const float* __restrict__ hz,       // (64,6624)
    const float* __restrict__ Wf,       // (16,32)
    const float* __restrict__ bf,       // (32,)
    const float* __restrict__ Wg,       // (16,256)
    const float* __restrict__ bg,       // (256,)
    const float* __restrict__ conv_w,   // (16,)
    float* __restrict__ inpT,           // (16560,64)
    int t)
{
    const int bn = blockIdx.x;
    const int n = bn % NODE;
    const int b = bn / NODE;
    const int tid = threadIdx.x;

    __shared__ float shz[32];
    __shared__ float sf[32];
    __shared__ float sg[256];

    if (tid < 32) shz[tid] = hz[(size_t)b * HIDDEN + n * 32 + tid];
    __syncthreads();

    // g[c] for c = tid (0..255): z = shz[2i+1]
    {
        float accg = bg[tid];
        #pragma unroll
        for (int i = 0; i < 16; ++i)
            accg = fmaf(shz[2 * i + 1], Wg[i * 256 + tid], accg);
        sg[tid] = tanhf(accg);
    }
    if (tid < 32) {
        // f[c] for c = tid: h = shz[2i]
        float accf = bf[tid];
        #pragma unroll
        for (int i = 0; i < 16; ++i)
            accf = fmaf(shz[2 * i], Wf[i * 32 + tid], accf);
        float fv = tanhf(accf);
        sf[tid] = fv;
        int i2 = tid >> 1, kk = tid & 1;
        int kf = 3312 + n * 64 + i2 * 4 + kk * 2;      // s = 0
        inpT[(size_t)kf * 64 + b] = fv;
    } else if (tid < 48) {
        int i = tid - 32;
        float v = spline[((((size_t)t * BATCH + b) * NODE + n) * 2) + 1];
        inpT[(size_t)(i * NODE + n) * 64 + b] = conv_w[i] * v;
    }
    __syncthreads();
    if (tid < 32) {
        int i2 = tid >> 1, kk = tid & 1;
        float acc = 0.f;
        #pragma unroll
        for (int j = 0; j < 16; ++j)
            acc = fmaf(sg[i2 * 16 + j], sf[j * 2 + kk], acc);
        int kfg = 3312 + n * 64 + i2 * 4 + kk * 2 + 1; // s = 1
        inpT[(size_t)kfg * 64 + b] = acc;
    }
}

// ---------------------------------------------------------------------------
// Kernel B: pre[b][j] += sum_k inp[b,k] * W_ih[j,k]  (bias folded into C).
// Grid: 207 j-tiles (32 rows) x 8 k-splits. Block: 256 thr = 64 b x 4 parts.
// Each (kc,p) pair q=kc*4+p handles float4-groups g = q, q+32, ... < 4140.
// W_ih read exactly once per step; inpT reads coalesced over b (lanes).
// ---------------------------------------------------------------------------
__global__ __launch_bounds__(256) void gemm_ih_kernel(
    const float* __restrict__ Wih,      // (6624,16560)
    const float* __restrict__ inpT,     // (16560,64)
    float* __restrict__ pre)            // (64,6624), pre-zeroed
{
    const int jt = blockIdx.x >> 3;     // 0..206
    const int kc = blockIdx.x & 7;      // 0..7
    const int j0 = jt * 32;
    const int tid = threadIdx.x;
    const int b = tid & 63;
    const int p = __builtin_amdgcn_readfirstlane(tid >> 6); // wave-uniform
    const int q = kc * 4 + p;           // 0..31

    float acc[32];
    #pragma unroll
    for (int jj = 0; jj < 32; ++jj) acc[jj] = 0.f;

    for (int g = q; g < K_IH4; g += 32) {
        const int k = g * 4;
        const float v0 = inpT[(size_t)(k + 0) * 64 + b];
        const float v1 = inpT[(size_t)(k + 1) * 64 + b];
        const float v2 = inpT[(size_t)(k + 2) * 64 + b];
        const float v3 = inpT[(size_t)(k + 3) * 64 + b];
        #pragma unroll
        for (int jj = 0; jj < 32; ++jj) {
            const float4 w = *reinterpret_cast<const float4*>(
                Wih + (size_t)(j0 + jj) * K_IH + k);
            acc[jj] = fmaf(w.x, v0, fmaf(w.y, v1, fmaf(w.z, v2, fmaf(w.w, v3, acc[jj]))));
        }
    }

    __shared__ float red[4][32][65];    // +1 pad to break bank conflicts
    #pragma unroll
    for (int jj = 0; jj < 32; ++jj) red[p][jj][b] = acc[jj];
    __syncthreads();

    for (int idx = tid; idx < 2048; idx += 256) {
        const int jj = idx & 31;
        const int b2 = idx >> 5;
        const float s = red[0][jj][b2] + red[1][jj][b2] + red[2][jj][b2] + red[3][jj][b2];
        atomicAdd(pre + (size_t)b2 * HIDDEN + j0 + jj, s);
    }
}

// ---------------------------------------------------------------------------
// Kernel C: 64 sequential RNN steps with a manual grid barrier.
//   h_b = tanh(pre[b] + h_{b-1} @ W_hh^T + b_hh + b_ih);  hz[b] = h_b
// Grid: 512 blocks x 256 thr (all co-resident; 2 blocks/CU). Each wave owns
// rows j = gw + s*2048. h_{b-1} staged in LDS per block per step.
// ---------------------------------------------------------------------------
__global__ __launch_bounds__(256) void rnn_kernel(
    const float* __restrict__ Whh,      // (6624,6624)
    const float* __restrict__ b_hh,     // (6624,)
    const float* __restrict__ b_ih,     // (6624,)
    const float* __restrict__ pre,      // (64,6624)
    float* __restrict__ hz,             // (64,6624) output (also h chain)
    unsigned int* __restrict__ bar,
    int bar_base)
{
    const int lane = threadIdx.x & 63;
    const int widx = threadIdx.x >> 6;
    const int gw = blockIdx.x * 4 + widx;
    const int nw = gridDim.x * 4;

    __shared__ float4 sh4[H4];          // 26.5 KB: h_{b-1}
    const float4* W4 = reinterpret_cast<const float4*>(Whh);

    for (int b = 0; b < 64; ++b) {
        if (b > 0) {
            const float4* hrow = reinterpret_cast<const float4*>(hz + (size_t)(b - 1) * HIDDEN);
            for (int idx = threadIdx.x; idx < H4; idx += 256) sh4[idx] = hrow[idx];
        }
        __syncthreads();

        for (int j = gw; j < HIDDEN; j += nw) {
            float a0 = 0.f, a1 = 0.f, a2 = 0.f, a3 = 0.f;
            if (b > 0) {
                const float4* Wrow = W4 + (size_t)j * H4;
                #pragma unroll 5
                for (int it = 0; it < 25; ++it) {
                    const float4 w = Wrow[it * 64 + lane];
                    const float4 h = sh4[it * 64 + lane];
                    a0 = fmaf(w.x, h.x, a0);
                    a1 = fmaf(w.y, h.y, a1);
                    a2 = fmaf(w.z, h.z, a2);
                    a3 = fmaf(w.w, h.w, a3);
                }
                if (lane < 56) {       // tail: 1656 = 25*64 + 56
                    const float4 w = Wrow[1600 + lane];
                    const float4 h = sh4[1600 + lane];
                    a0 = fmaf(w.x, h.x, a0);
                    a1 = fmaf(w.y, h.y, a1);
                    a2 = fmaf(w.z, h.z, a2);
                    a3 = fmaf(w.w, h.w, a3);
                }
            }
            float acc = (a0 + a1) + (a2 + a3);
            #pragma unroll
            for (int off = 32; off > 0; off >>= 1) acc += __shfl_xor(acc, off, 64);
            if (lane == 0) {
                const float v = tanhf(pre[(size_t)b * HIDDEN + j] + acc + b_hh[j] + b_ih[j]);
                hz[(size_t)b * HIDDEN + j] = v;
            }
        }

        if (b != 63) {
            __syncthreads();
            if (threadIdx.x == 0) {
                __threadfence();   // agent-scope release of this block's hz stores
                __hip_atomic_fetch_add(bar, 1u, __ATOMIC_ACQ_REL, __HIP_MEMORY_SCOPE_AGENT);
                const unsigned int target =
                    (unsigned int)gridDim.x * (unsigned int)(bar_base + b + 1);
                while (__hip_atomic_load(bar, __ATOMIC_ACQUIRE, __HIP_MEMORY_SCOPE_AGENT) < target) {
                    __builtin_amdgcn_s_sleep(2);
                }
            }
            __syncthreads();
        }
    }
}

// ---------------------------------------------------------------------------
extern "C" void kernel_launch(void* const* d_in, const int* in_sizes, int n_in,
                              void* d_out, int out_size, void* d_ws, size_t ws_size,
                              hipStream_t stream)
{
    const float* spline = (const float*)d_in[0];   // (12,64,207,2)
    const float* init0  = (const float*)d_in[1];   // (64,6624)
    const float* Wf     = (const float*)d_in[2];   // (16,32)
    const float* bf     = (const float*)d_in[3];   // (32,)
    const float* Wg     = (const float*)d_in[4];   // (16,256)
    const float* bg     = (const float*)d_in[5];   // (256,)
    const float* conv_w = (const float*)d_in[6];   // (16,)
    const float* Wih    = (const float*)d_in[7];   // (6624,16560)
    const float* b_ih   = (const float*)d_in[8];   // (6624,)
    const float* Whh    = (const float*)d_in[9];   // (6624,6624)
    const float* b_hh   = (const float*)d_in[10];  // (6624,)
    float* out = (float*)d_out;

    char* ws = (char*)d_ws;
    unsigned int* bar = (unsigned int*)ws;                       // 256 B slot
    float* inpT  = (float*)(ws + 256);                           // 4,239,360 B
    float* pre   = (float*)(ws + 256 + (size_t)K_IH * 64 * 4);   // 1,695,744 B
    float* hz_ws = (float*)(ws + 256 + (size_t)K_IH * 64 * 4
                                  + (size_t)BATCH * HIDDEN * 4); // 1,695,744 B

    hipMemsetAsync(bar, 0, 256, stream);

    for (int t = 0; t < TSTEPS; ++t) {
        const float* hz_in = (t == 0) ? init0 : hz_ws;
        float* hz_out = (t == TSTEPS - 1) ? out : hz_ws;

        build_inp_kernel<<<BATCH * NODE, 256, 0, stream>>>(
            spline, hz_in, Wf, bf, Wg, bg, conv_w, inpT, t);

        hipMemsetAsync(pre, 0, (size_t)BATCH * HIDDEN * sizeof(float), stream);

        gemm_ih_kernel<<<207 * 8, 256, 0, stream>>>(Wih, inpT, pre);

        rnn_kernel<<<512, 256, 0, stream>>>(
            Whh, b_hh, b_ih, pre, hz_out, bar, t * 63);
    }
}